// Round 1
// baseline (752.772 us; speedup 1.0000x reference)
//
#include <hip/hip_runtime.h>
#include <cmath>

// DeepSeek MoE layer, MI355X (gfx950). Round 4.
// B=2,S=1024 -> T=2048 tokens. H=1024, FF=4096, E=64, K=8, M=512.
//
// Round-4 changes vs round 3 (which was latency-bound: MfmaUtil 8%,
// VALUBusy 10%, HBM 15% on g_exp1 — every pipe idle, stalled on the
// per-iteration vmcnt(0) drain that __syncthreads forces on the
// just-issued global_load_lds stage):
//  - GEMM core -> m97 geometry: 128x128 tile, BK=32, 4 waves (2x2 of
//    64x64), acc[4][4], 16 MFMA + 8 ds_read_b128 per wave-iter
//    (2x better MFMA:LDS ratio than the 64x128 tile).
//  - 3-buffer depth-2 software pipeline with COUNTED vmcnt and raw
//    s_barrier: prologue stages k=0,1; steady state waits vmcnt(4)
//    (one 4-instr stage stays in flight across the barrier), stages
//    k+2 after the barrier. vmcnt never drains to 0 in the main loop.
//    Race safety: each wave waits its own stage's vmcnt before the
//    barrier (buffer full after barrier); buffer read at iter t is
//    only re-staged after barrier t+1, and every wave's ds_reads are
//    complete before it reaches that barrier (lgkmcnt before MFMA).
//  - LDS 3 x (8KB A + 8KB B) = 48KB -> up to 3 blocks/CU.

typedef _Float16 f16;
typedef __attribute__((ext_vector_type(4))) _Float16 f16x4;
typedef __attribute__((ext_vector_type(8))) _Float16 f16x8;
typedef __attribute__((ext_vector_type(4))) float f32x4;

#define NT 2048      // tokens
#define HD 1024      // hidden
#define FF 4096      // shared intermediate
#define NE 64        // experts
#define TOPK 8
#define MD 512       // moe intermediate

// ---- workspace layout (bytes) ----
constexpr size_t SZ_H1 = (size_t)NT * FF * 2;                // fp16 [2048][4096]
constexpr size_t SZ_HX = (size_t)(NT * TOPK + 128) * MD * 2; // fp16 [16512][512]
constexpr size_t O_H1 = 0;
constexpr size_t O_HX = O_H1 + SZ_H1;
constexpr size_t O_TOPKI = O_HX + SZ_HX;
constexpr size_t O_TOPKW = O_TOPKI + (size_t)NT * TOPK * 4;
constexpr size_t O_COUNTS = O_TOPKW + (size_t)NT * TOPK * 4;
constexpr size_t O_CURSORS = O_COUNTS + 256;
constexpr size_t O_OFFSETS = O_CURSORS + 256;
constexpr size_t O_RTOK = O_OFFSETS + 256;
constexpr size_t O_RW = O_RTOK + (size_t)NT * TOPK * 4;
constexpr size_t O_XH = ((O_RW + (size_t)NT * TOPK * 4 + 255) / 256) * 256;
constexpr size_t O_W1T = O_XH + (size_t)NT * HD * 2;         // fp16 [E][M][H]
constexpr size_t O_W2T = O_W1T + (size_t)NE * HD * MD * 2;   // fp16 [E][H][M]
constexpr size_t O_WS1T = O_W2T + (size_t)NE * MD * HD * 2;  // fp16 [FF][H]
constexpr size_t O_WS2T = O_WS1T + (size_t)HD * FF * 2;      // fp16 [H][FF]
constexpr size_t WS_NEEDED = O_WS2T + (size_t)FF * HD * 2;   // ~189 MB

// async global->LDS, 16B per lane; lane i lands at ldsbase + i*16.
__device__ __forceinline__ void lds16(void* l, const void* g) {
    __builtin_amdgcn_global_load_lds(
        (const __attribute__((address_space(1))) void*)g,
        (__attribute__((address_space(3))) void*)l, 16, 0, 0);
}

// ------------------------------------------------------------------
// router: logits[t][e] = dot(x[t], Wg[:,e]) in fp32 (must match numpy top-k).
__global__ __launch_bounds__(256) void k_router(const float* __restrict__ X,
                                                const float* __restrict__ Wg,
                                                float* __restrict__ logits)
{
    __shared__ float xs[4][HD];
    const int tid = threadIdx.x;
    const int t0 = blockIdx.x * 4;
    #pragma unroll
    for (int i = 0; i < 4; ++i) {
        int f4 = tid + i * 256;
        int row = f4 >> 8;
        int col = (f4 & 255) * 4;
        *(float4*)&xs[row][col] = *(const float4*)&X[(t0 + row) * HD + col];
    }
    __syncthreads();
    const int e = tid & 63, tok = tid >> 6;
    float a0 = 0.f, a1 = 0.f, a2 = 0.f, a3 = 0.f;
    const float* xr = xs[tok];
    for (int h = 0; h < HD; h += 4) {
        a0 += xr[h + 0] * Wg[(h + 0) * NE + e];
        a1 += xr[h + 1] * Wg[(h + 1) * NE + e];
        a2 += xr[h + 2] * Wg[(h + 2) * NE + e];
        a3 += xr[h + 3] * Wg[(h + 3) * NE + e];
    }
    logits[(t0 + tok) * NE + e] = (a0 + a1) + (a2 + a3);
}

// top-8 + softmax per token; one wave per token; tie-break lower index.
__global__ __launch_bounds__(64) void k_topk(const float* __restrict__ logits,
                                             int* __restrict__ topk_idx,
                                             float* __restrict__ topk_w,
                                             int* __restrict__ counts)
{
    const int t = blockIdx.x;
    const int lane = threadIdx.x;
    __shared__ float sval[TOPK];
    __shared__ int sidx[TOPK];
    float cur = logits[t * NE + lane];
    for (int it = 0; it < TOPK; ++it) {
        float v = cur; int id = lane;
        #pragma unroll
        for (int off = 32; off > 0; off >>= 1) {
            float ov = __shfl_xor(v, off, 64);
            int   oi = __shfl_xor(id, off, 64);
            if (ov > v || (ov == v && oi < id)) { v = ov; id = oi; }
        }
        if (lane == 0) { sval[it] = v; sidx[it] = id; }
        if (lane == id) cur = -INFINITY;
    }
    __syncthreads();
    if (lane < TOPK) {
        float m = sval[0];
        float denom = 0.f;
        #pragma unroll
        for (int j = 0; j < TOPK; ++j) denom += expf(sval[j] - m);
        float w = expf(sval[lane] - m) / denom;
        int e = sidx[lane];
        topk_idx[t * TOPK + lane] = e;
        topk_w[t * TOPK + lane] = w;
        atomicAdd(&counts[e], 1);
    }
}

__global__ void k_scan(const int* __restrict__ counts, int* __restrict__ offsets)
{
    if (threadIdx.x == 0) {
        int run = 0;
        for (int e = 0; e < NE; ++e) { offsets[e] = run; run += counts[e]; }
    }
}

__global__ __launch_bounds__(256) void k_route(const int* __restrict__ topk_idx,
                                               const float* __restrict__ topk_w,
                                               const int* __restrict__ offsets,
                                               int* __restrict__ cursors,
                                               int* __restrict__ rtok,
                                               float* __restrict__ rw)
{
    int i = blockIdx.x * 256 + threadIdx.x;
    int e = topk_idx[i];
    int pos = atomicAdd(&cursors[e], 1);
    int slot = offsets[e] + pos;
    rtok[slot] = i >> 3;
    rw[slot] = topk_w[i];
}

// ------------------------------------------------------------------
// conversion pre-pass
__global__ __launch_bounds__(256) void k_cvt_x(const float* __restrict__ X,
                                               f16* __restrict__ Xh)
{
    int i = blockIdx.x * 256 + threadIdx.x;
    float4 v = ((const float4*)X)[i];
    f16x4 h = { (f16)v.x, (f16)v.y, (f16)v.z, (f16)v.w };
    ((f16x4*)Xh)[i] = h;
}

// fp32 [K][N] -> fp16 [N][K] (transpose), batched over blockIdx.z.
__global__ __launch_bounds__(256) void k_cvt_t(const float* __restrict__ src,
                                               f16* __restrict__ dst,
                                               int K, int N)
{
    const size_t bofs = (size_t)blockIdx.z * K * N;
    src += bofs; dst += bofs;
    const int n0 = blockIdx.x * 64, k0 = blockIdx.y * 64;
    __shared__ f16 t[64][68];
    const int tid = threadIdx.x;
    #pragma unroll
    for (int i = 0; i < 4; ++i) {
        int idx = tid + i * 256;
        int r = idx >> 4, c4 = (idx & 15) * 4;
        float4 v = *(const float4*)&src[(size_t)(k0 + r) * N + n0 + c4];
        f16x4 h = { (f16)v.x, (f16)v.y, (f16)v.z, (f16)v.w };
        *(f16x4*)&t[r][c4] = h;
    }
    __syncthreads();
    #pragma unroll
    for (int i = 0; i < 4; ++i) {
        int idx = tid + i * 256;
        int nr = idx >> 4, kc = (idx & 15) * 4;
        f16x4 o = { t[kc][nr], t[kc + 1][nr], t[kc + 2][nr], t[kc + 3][nr] };
        *(f16x4*)&dst[(size_t)(n0 + nr) * K + k0 + kc] = o;
    }
}

// ------------------------------------------------------------------
// GEMM core: 128x128 tile, BK=32, 4 waves (2 M-halves x 2 N-halves),
// wave = 64x64 = acc[4][4]. 3-buffer depth-2 pipeline, counted vmcnt,
// raw s_barrier (one per iter). LDS per buffer: As 128x32, Bs 128x32.
// Frag mapping (verified r0-r3): A[m=fr][k=q*8+j], B[n=fr][k=q*8+j],
// C/D col=fr, row=q*4+reg.

#define GEMM_PREAMBLE                                                        \
    const int tid = threadIdx.x, lane = tid & 63, wave = tid >> 6;           \
    const int wm = (wave >> 1) * 64, wn = (wave & 1) * 64;                   \
    const int fr = lane & 15, q = lane >> 4;                                 \
    const int sr = lane >> 2, sc = (lane & 3) * 8;

#define GEMM_LDS                                                             \
    __shared__ alignas(16) f16 As[3][128 * 32];                              \
    __shared__ alignas(16) f16 Bs[3][128 * 32];

// one stage = 4 global_load_lds instructions per thread (16KB/tile).
#define GEMM_STAGE(si, ofs)                                                  \
    lds16(&As[si][wave * 32 * 32], gA0 + (ofs));                             \
    lds16(&As[si][(wave * 32 + 16) * 32], gA1 + (ofs));                      \
    lds16(&Bs[si][wave * 32 * 32], gB0 + (ofs));                             \
    lds16(&Bs[si][(wave * 32 + 16) * 32], gB1 + (ofs));

#define GEMM_MFMA(ri)                                                        \
    {                                                                        \
        f16x8 af[4], bf[4];                                                  \
        _Pragma("unroll")                                                    \
        for (int i = 0; i < 4; ++i)                                          \
            af[i] = *(const f16x8*)&As[ri][(wm + i * 16 + fr) * 32 + q * 8]; \
        _Pragma("unroll")                                                    \
        for (int j = 0; j < 4; ++j)                                          \
            bf[j] = *(const f16x8*)&Bs[ri][(wn + j * 16 + fr) * 32 + q * 8]; \
        _Pragma("unroll")                                                    \
        for (int i = 0; i < 4; ++i)                                          \
            _Pragma("unroll")                                                \
            for (int j = 0; j < 4; ++j)                                      \
                acc[i][j] = __builtin_amdgcn_mfma_f32_16x16x32_f16(          \
                    af[i], bf[j], acc[i][j], 0, 0, 0);                       \
    }

// Pipelined K-loop. Prologue stages k=0,1 into buffers 0,1. Steady state:
// wait vmcnt(4) [stage t landed; stage t+1 still in flight], barrier,
// issue stage t+2, compute tile t. Loads are never drained to 0 until
// the final iteration.
#define GEMM_LOOP(KITERS)                                                    \
    GEMM_STAGE(0, 0)                                                         \
    GEMM_STAGE(1, 32)                                                        \
    {                                                                        \
        int ri = 0, ni = 1, si = 2;                                          \
        for (int t = 0; t < (KITERS); ++t) {                                 \
            if (t < (KITERS) - 1)                                            \
                asm volatile("s_waitcnt vmcnt(4)" ::: "memory");             \
            else                                                             \
                asm volatile("s_waitcnt vmcnt(0)" ::: "memory");             \
            __builtin_amdgcn_s_barrier();                                    \
            asm volatile("" ::: "memory");                                   \
            if (t + 2 < (KITERS)) { GEMM_STAGE(si, (t + 2) * 32) }           \
            GEMM_MFMA(ri)                                                    \
            int tmp = ri; ri = ni; ni = si; si = tmp;                        \
        }                                                                    \
    }

// shared GEMM1: H1 = silu(Xh @ Ws1), fp16. M=2048 N=4096 K=1024.
__global__ __launch_bounds__(256) void g_shared1(const f16* __restrict__ Xh,
                                                 const f16* __restrict__ Bt,  // [FF][HD]
                                                 f16* __restrict__ H1)
{
    GEMM_LDS
    GEMM_PREAMBLE
    const int m0 = blockIdx.y * 128, n0 = blockIdx.x * 128;
    const f16* gA0 = Xh + (size_t)(m0 + wave * 32 + sr) * HD + sc;
    const f16* gA1 = gA0 + (size_t)16 * HD;
    const f16* gB0 = Bt + (size_t)(n0 + wave * 32 + sr) * HD + sc;
    const f16* gB1 = gB0 + (size_t)16 * HD;

    f32x4 acc[4][4] = {};
    GEMM_LOOP(HD / 32)

    #pragma unroll
    for (int i = 0; i < 4; ++i)
        #pragma unroll
        for (int j = 0; j < 4; ++j)
            #pragma unroll
            for (int r = 0; r < 4; ++r) {
                int m = m0 + wm + i * 16 + q * 4 + r;
                int n = n0 + wn + j * 16 + fr;
                float v = acc[i][j][r];
                H1[(size_t)m * FF + n] = (f16)(v / (1.f + expf(-v)));
            }
}

// shared GEMM2: Out += H1 @ Ws2, split-K=4 atomics. M=2048 N=1024 K=4096.
__global__ __launch_bounds__(256) void g_shared2(const f16* __restrict__ H1,
                                                 const f16* __restrict__ Bt,  // [HD][FF]
                                                 float* __restrict__ Out)
{
    GEMM_LDS
    GEMM_PREAMBLE
    const int m0 = blockIdx.y * 128, n0 = blockIdx.x * 128;
    const int kbase = blockIdx.z * (FF / 4);
    const f16* gA0 = H1 + (size_t)(m0 + wave * 32 + sr) * FF + kbase + sc;
    const f16* gA1 = gA0 + (size_t)16 * FF;
    const f16* gB0 = Bt + (size_t)(n0 + wave * 32 + sr) * FF + kbase + sc;
    const f16* gB1 = gB0 + (size_t)16 * FF;

    f32x4 acc[4][4] = {};
    GEMM_LOOP((FF / 4) / 32)

    #pragma unroll
    for (int i = 0; i < 4; ++i)
        #pragma unroll
        for (int j = 0; j < 4; ++j)
            #pragma unroll
            for (int r = 0; r < 4; ++r) {
                int m = m0 + wm + i * 16 + q * 4 + r;
                int n = n0 + wn + j * 16 + fr;
                atomicAdd(&Out[(size_t)m * HD + n], acc[i][j][r]);
            }
}

// expert GEMM1: Hx[slot] = silu(Xh[rtok[slot]] @ W1[e]) fp16. K=1024 N=512.
__global__ __launch_bounds__(256) void g_exp1(const f16* __restrict__ Xh,
                                              const f16* __restrict__ W1t, // [E][M][H]
                                              const int* __restrict__ counts,
                                              const int* __restrict__ offsets,
                                              const int* __restrict__ rtok,
                                              f16* __restrict__ Hx)
{
    const int e = blockIdx.z;
    const int cnt = counts[e];
    const int mt = blockIdx.y * 128;
    if (mt >= cnt) return;
    const int off = offsets[e];
    const int n0 = blockIdx.x * 128;
    const f16* W = W1t + (size_t)e * MD * HD;

    GEMM_LDS
    GEMM_PREAMBLE

    int rm0 = mt + wave * 32 + sr;
    int rm1 = rm0 + 16;
    int s0 = off + (rm0 < cnt ? rm0 : cnt - 1);
    int s1 = off + (rm1 < cnt ? rm1 : cnt - 1);
    const f16* gA0 = Xh + (size_t)rtok[s0] * HD + sc;
    const f16* gA1 = Xh + (size_t)rtok[s1] * HD + sc;
    const f16* gB0 = W + (size_t)(n0 + wave * 32 + sr) * HD + sc;
    const f16* gB1 = gB0 + (size_t)16 * HD;

    f32x4 acc[4][4] = {};
    GEMM_LOOP(HD / 32)

    #pragma unroll
    for (int i = 0; i < 4; ++i)
        #pragma unroll
        for (int j = 0; j < 4; ++j)
            #pragma unroll
            for (int r = 0; r < 4; ++r) {
                int m_in = mt + wm + i * 16 + q * 4 + r;
                if (m_in < cnt) {
                    int n = n0 + wn + j * 16 + fr;
                    float v = acc[i][j][r];
                    Hx[(size_t)(off + m_in) * MD + n] = (f16)(v / (1.f + expf(-v)));
                }
            }
}

// expert GEMM2: Out[t] += w * (Hx @ W2[e]). K=512 N=1024, atomic scatter.
__global__ __launch_bounds__(256) void g_exp2(const f16* __restrict__ Hx,
                                              const f16* __restrict__ W2t, // [E][H][M]
                                              const int* __restrict__ counts,
                                              const int* __restrict__ offsets,
                                              const int* __restrict__ rtok,
                                              const float* __restrict__ rw,
                                              float* __restrict__ Out)
{
    const int e = blockIdx.z;
    const int cnt = counts[e];
    const int mt = blockIdx.y * 128;
    if (mt >= cnt) return;
    const int off = offsets[e];
    const int n0 = blockIdx.x * 128;
    const f16* W = W2t + (size_t)e * HD * MD;

    GEMM_LDS
    GEMM_PREAMBLE

    // A rows are packed slots; Hx pad rows (128) make OOB reads safe
    // (masked at C).
    const f16* gA0 = Hx + (size_t)(off + mt + wave * 32 + sr) * MD + sc;
    const f16* gA1 = gA0 + (size_t)16 * MD;
    const f16* gB0 = W + (size_t)(n0 + wave * 32 + sr) * MD + sc;
    const f16* gB1 = gB0 + (size_t)16 * MD;

    f32x4 acc[4][4] = {};
    GEMM_LOOP(MD / 32)

    #pragma unroll
    for (int i = 0; i < 4; ++i)
        #pragma unroll
        for (int r = 0; r < 4; ++r) {
            int m_in = mt + wm + i * 16 + q * 4 + r;
            if (m_in < cnt) {
                int slot = off + m_in;
                int t = rtok[slot];
                float w = rw[slot];
                float* orow = Out + (size_t)t * HD + n0 + wn + fr;
                #pragma unroll
                for (int j = 0; j < 4; ++j)
                    atomicAdd(&orow[j * 16], w * acc[i][j][r]);
            }
        }
}

// ------------------------------------------------------------------
extern "C" void kernel_launch(void* const* d_in, const int* in_sizes, int n_in,
                              void* d_out, int out_size, void* d_ws, size_t ws_size,
                              hipStream_t stream)
{
    (void)in_sizes; (void)n_in; (void)out_size; (void)ws_size;
    const float* X   = (const float*)d_in[0];
    const float* Ws1 = (const float*)d_in[1];
    const float* Ws2 = (const float*)d_in[2];
    const float* Wg  = (const float*)d_in[3];
    const float* W1  = (const float*)d_in[4];
    const float* W2  = (const float*)d_in[5];
    float* out = (float*)d_out;
    float* logits = out + (size_t)NT * HD;

    char* ws = (char*)d_ws;
    f16*   h1       = (f16*)(ws + O_H1);
    f16*   hx       = (f16*)(ws + O_HX);
    int*   topk_idx = (int*)(ws + O_TOPKI);
    float* topk_w   = (float*)(ws + O_TOPKW);
    int*   counts   = (int*)(ws + O_COUNTS);
    int*   cursors  = (int*)(ws + O_CURSORS);
    int*   offsets  = (int*)(ws + O_OFFSETS);
    int*   rtok     = (int*)(ws + O_RTOK);
    float* rwt      = (float*)(ws + O_RW);
    f16*   xh       = (f16*)(ws + O_XH);
    f16*   w1t      = (f16*)(ws + O_W1T);
    f16*   w2t      = (f16*)(ws + O_W2T);
    f16*   ws1t     = (f16*)(ws + O_WS1T);
    f16*   ws2t     = (f16*)(ws + O_WS2T);

    hipMemsetAsync(counts, 0, 512, stream);   // counts + cursors

    k_router<<<NT / 4, 256, 0, stream>>>(X, Wg, logits);
    k_topk<<<NT, 64, 0, stream>>>(logits, topk_idx, topk_w, counts);
    k_scan<<<1, 64, 0, stream>>>(counts, offsets);
    k_route<<<NT * TOPK / 256, 256, 0, stream>>>(topk_idx, topk_w, offsets, cursors, rtok, rwt);

    // conversion pre-pass
    k_cvt_x<<<NT * HD / 1024, 256, 0, stream>>>(X, xh);
    k_cvt_t<<<dim3(FF / 64, HD / 64, 1), 256, 0, stream>>>(Ws1, ws1t, HD, FF);
    k_cvt_t<<<dim3(HD / 64, FF / 64, 1), 256, 0, stream>>>(Ws2, ws2t, FF, HD);
    k_cvt_t<<<dim3(MD / 64, HD / 64, NE), 256, 0, stream>>>(W1, w1t, HD, MD);
    k_cvt_t<<<dim3(HD / 64, MD / 64, NE), 256, 0, stream>>>(W2, w2t, MD, HD);
    hipMemsetAsync(out, 0, (size_t)NT * HD * 4, stream);

    g_shared1<<<dim3(FF / 128, NT / 128), 256, 0, stream>>>(xh, ws1t, h1);
    g_shared2<<<dim3(HD / 128, NT / 128, 4), 256, 0, stream>>>(h1, ws2t, out);
    g_exp1<<<dim3(MD / 128, NT / 128, NE), 256, 0, stream>>>(xh, w1t, counts, offsets, rtok, hx);
    g_exp2<<<dim3(HD / 128, NT / 128, NE), 256, 0, stream>>>(hx, w2t, counts, offsets, rtok, rwt, out);
}

// Round 2
// 687.546 us; speedup vs baseline: 1.0949x; 1.0949x over previous
//
#include <hip/hip_runtime.h>
#include <cmath>

// DeepSeek MoE layer, MI355X (gfx950). Round 5.
// B=2,S=1024 -> T=2048 tokens. H=1024, FF=4096, E=64, K=8, M=512.
//
// Round-5 = round-3 geometry + round-4 pipeline (decoupled post-mortem):
//  - Round 4 (128x128 tile) regressed because expert GEMMs have only
//    ~256 rows/expert -> 512 active blocks -> 2 blocks/CU -> nothing
//    co-resident to overlap. Occupancy dominates pipeline depth.
//  - Tile back to 64x128, BK=32, 4 waves (2x2 of 32x64), acc[2][4]:
//    1024+ active blocks on every GEMM.
//  - KEEP the 3-buffer depth-2 counted-vmcnt pipeline: stage = 3
//    global_load_lds / thread; steady state waits vmcnt(3) (stage t+1
//    stays in flight across the barrier), issues stage t+2 after the
//    barrier; vmcnt drains to 0 only on the last iteration.
//  - LDS 3 x 12KB = 36KB -> 4 blocks/CU (144KB of 160KB).

typedef _Float16 f16;
typedef __attribute__((ext_vector_type(4))) _Float16 f16x4;
typedef __attribute__((ext_vector_type(8))) _Float16 f16x8;
typedef __attribute__((ext_vector_type(4))) float f32x4;

#define NT 2048      // tokens
#define HD 1024      // hidden
#define FF 4096      // shared intermediate
#define NE 64        // experts
#define TOPK 8
#define MD 512       // moe intermediate

// ---- workspace layout (bytes) ----
constexpr size_t SZ_H1 = (size_t)NT * FF * 2;                // fp16 [2048][4096]
constexpr size_t SZ_HX = (size_t)(NT * TOPK + 128) * MD * 2; // fp16 [16512][512]
constexpr size_t O_H1 = 0;
constexpr size_t O_HX = O_H1 + SZ_H1;
constexpr size_t O_TOPKI = O_HX + SZ_HX;
constexpr size_t O_TOPKW = O_TOPKI + (size_t)NT * TOPK * 4;
constexpr size_t O_COUNTS = O_TOPKW + (size_t)NT * TOPK * 4;
constexpr size_t O_CURSORS = O_COUNTS + 256;
constexpr size_t O_OFFSETS = O_CURSORS + 256;
constexpr size_t O_RTOK = O_OFFSETS + 256;
constexpr size_t O_RW = O_RTOK + (size_t)NT * TOPK * 4;
constexpr size_t O_XH = ((O_RW + (size_t)NT * TOPK * 4 + 255) / 256) * 256;
constexpr size_t O_W1T = O_XH + (size_t)NT * HD * 2;         // fp16 [E][M][H]
constexpr size_t O_W2T = O_W1T + (size_t)NE * HD * MD * 2;   // fp16 [E][H][M]
constexpr size_t O_WS1T = O_W2T + (size_t)NE * MD * HD * 2;  // fp16 [FF][H]
constexpr size_t O_WS2T = O_WS1T + (size_t)HD * FF * 2;      // fp16 [H][FF]
constexpr size_t WS_NEEDED = O_WS2T + (size_t)FF * HD * 2;   // ~189 MB

// async global->LDS, 16B per lane; lane i lands at ldsbase + i*16.
__device__ __forceinline__ void lds16(void* l, const void* g) {
    __builtin_amdgcn_global_load_lds(
        (const __attribute__((address_space(1))) void*)g,
        (__attribute__((address_space(3))) void*)l, 16, 0, 0);
}

// ------------------------------------------------------------------
// router: logits[t][e] = dot(x[t], Wg[:,e]) in fp32 (must match numpy top-k).
__global__ __launch_bounds__(256) void k_router(const float* __restrict__ X,
                                                const float* __restrict__ Wg,
                                                float* __restrict__ logits)
{
    __shared__ float xs[4][HD];
    const int tid = threadIdx.x;
    const int t0 = blockIdx.x * 4;
    #pragma unroll
    for (int i = 0; i < 4; ++i) {
        int f4 = tid + i * 256;
        int row = f4 >> 8;
        int col = (f4 & 255) * 4;
        *(float4*)&xs[row][col] = *(const float4*)&X[(t0 + row) * HD + col];
    }
    __syncthreads();
    const int e = tid & 63, tok = tid >> 6;
    float a0 = 0.f, a1 = 0.f, a2 = 0.f, a3 = 0.f;
    const float* xr = xs[tok];
    for (int h = 0; h < HD; h += 4) {
        a0 += xr[h + 0] * Wg[(h + 0) * NE + e];
        a1 += xr[h + 1] * Wg[(h + 1) * NE + e];
        a2 += xr[h + 2] * Wg[(h + 2) * NE + e];
        a3 += xr[h + 3] * Wg[(h + 3) * NE + e];
    }
    logits[(t0 + tok) * NE + e] = (a0 + a1) + (a2 + a3);
}

// top-8 + softmax per token; one wave per token; tie-break lower index.
__global__ __launch_bounds__(64) void k_topk(const float* __restrict__ logits,
                                             int* __restrict__ topk_idx,
                                             float* __restrict__ topk_w,
                                             int* __restrict__ counts)
{
    const int t = blockIdx.x;
    const int lane = threadIdx.x;
    __shared__ float sval[TOPK];
    __shared__ int sidx[TOPK];
    float cur = logits[t * NE + lane];
    for (int it = 0; it < TOPK; ++it) {
        float v = cur; int id = lane;
        #pragma unroll
        for (int off = 32; off > 0; off >>= 1) {
            float ov = __shfl_xor(v, off, 64);
            int   oi = __shfl_xor(id, off, 64);
            if (ov > v || (ov == v && oi < id)) { v = ov; id = oi; }
        }
        if (lane == 0) { sval[it] = v; sidx[it] = id; }
        if (lane == id) cur = -INFINITY;
    }
    __syncthreads();
    if (lane < TOPK) {
        float m = sval[0];
        float denom = 0.f;
        #pragma unroll
        for (int j = 0; j < TOPK; ++j) denom += expf(sval[j] - m);
        float w = expf(sval[lane] - m) / denom;
        int e = sidx[lane];
        topk_idx[t * TOPK + lane] = e;
        topk_w[t * TOPK + lane] = w;
        atomicAdd(&counts[e], 1);
    }
}

__global__ void k_scan(const int* __restrict__ counts, int* __restrict__ offsets)
{
    if (threadIdx.x == 0) {
        int run = 0;
        for (int e = 0; e < NE; ++e) { offsets[e] = run; run += counts[e]; }
    }
}

__global__ __launch_bounds__(256) void k_route(const int* __restrict__ topk_idx,
                                               const float* __restrict__ topk_w,
                                               const int* __restrict__ offsets,
                                               int* __restrict__ cursors,
                                               int* __restrict__ rtok,
                                               float* __restrict__ rw)
{
    int i = blockIdx.x * 256 + threadIdx.x;
    int e = topk_idx[i];
    int pos = atomicAdd(&cursors[e], 1);
    int slot = offsets[e] + pos;
    rtok[slot] = i >> 3;
    rw[slot] = topk_w[i];
}

// ------------------------------------------------------------------
// conversion pre-pass
__global__ __launch_bounds__(256) void k_cvt_x(const float* __restrict__ X,
                                               f16* __restrict__ Xh)
{
    int i = blockIdx.x * 256 + threadIdx.x;
    float4 v = ((const float4*)X)[i];
    f16x4 h = { (f16)v.x, (f16)v.y, (f16)v.z, (f16)v.w };
    ((f16x4*)Xh)[i] = h;
}

// fp32 [K][N] -> fp16 [N][K] (transpose), batched over blockIdx.z.
__global__ __launch_bounds__(256) void k_cvt_t(const float* __restrict__ src,
                                               f16* __restrict__ dst,
                                               int K, int N)
{
    const size_t bofs = (size_t)blockIdx.z * K * N;
    src += bofs; dst += bofs;
    const int n0 = blockIdx.x * 64, k0 = blockIdx.y * 64;
    __shared__ f16 t[64][68];
    const int tid = threadIdx.x;
    #pragma unroll
    for (int i = 0; i < 4; ++i) {
        int idx = tid + i * 256;
        int r = idx >> 4, c4 = (idx & 15) * 4;
        float4 v = *(const float4*)&src[(size_t)(k0 + r) * N + n0 + c4];
        f16x4 h = { (f16)v.x, (f16)v.y, (f16)v.z, (f16)v.w };
        *(f16x4*)&t[r][c4] = h;
    }
    __syncthreads();
    #pragma unroll
    for (int i = 0; i < 4; ++i) {
        int idx = tid + i * 256;
        int nr = idx >> 4, kc = (idx & 15) * 4;
        f16x4 o = { t[kc][nr], t[kc + 1][nr], t[kc + 2][nr], t[kc + 3][nr] };
        *(f16x4*)&dst[(size_t)(n0 + nr) * K + k0 + kc] = o;
    }
}

// ------------------------------------------------------------------
// GEMM core: 64x128 tile, BK=32, 4 waves (2 M-halves x 2 N-halves),
// wave = 32x64 = acc[2][4]. 3-buffer depth-2 pipeline, counted vmcnt,
// raw s_barrier (one per iter). LDS/buffer: As 64x32, Bs 128x32 (12KB).
// Frag mapping (verified r0-r4): A[m=fr][k=q*8+j], B[n=fr][k=q*8+j],
// C/D col=fr, row=q*4+reg.

#define GEMM_PREAMBLE                                                        \
    const int tid = threadIdx.x, lane = tid & 63, wave = tid >> 6;           \
    const int wm = (wave >> 1) * 32, wn = (wave & 1) * 64;                   \
    const int fr = lane & 15, q = lane >> 4;                                 \
    const int sr = lane >> 2, sc = (lane & 3) * 8;

#define GEMM_LDS                                                             \
    __shared__ alignas(16) f16 As[3][64 * 32];                               \
    __shared__ alignas(16) f16 Bs[3][128 * 32];

// one stage = 3 global_load_lds instructions per thread (12KB/tile).
#define GEMM_STAGE(si, ofs)                                                  \
    lds16(&As[si][wave * 16 * 32], gA + (ofs));                              \
    lds16(&Bs[si][wave * 32 * 32], gB0 + (ofs));                             \
    lds16(&Bs[si][(wave * 32 + 16) * 32], gB1 + (ofs));

#define GEMM_MFMA(ri)                                                        \
    {                                                                        \
        f16x8 af[2], bf[4];                                                  \
        _Pragma("unroll")                                                    \
        for (int i = 0; i < 2; ++i)                                          \
            af[i] = *(const f16x8*)&As[ri][(wm + i * 16 + fr) * 32 + q * 8]; \
        _Pragma("unroll")                                                    \
        for (int j = 0; j < 4; ++j)                                          \
            bf[j] = *(const f16x8*)&Bs[ri][(wn + j * 16 + fr) * 32 + q * 8]; \
        _Pragma("unroll")                                                    \
        for (int i = 0; i < 2; ++i)                                          \
            _Pragma("unroll")                                                \
            for (int j = 0; j < 4; ++j)                                      \
                acc[i][j] = __builtin_amdgcn_mfma_f32_16x16x32_f16(          \
                    af[i], bf[j], acc[i][j], 0, 0, 0);                       \
    }

// Pipelined K-loop. Prologue stages k=0,1 into buffers 0,1. Steady state:
// wait vmcnt(3) [stage t landed; stage t+1 (3 loads) still in flight],
// barrier, issue stage t+2, compute tile t. Loads are never drained to 0
// until the final iteration.
// Race safety (unchanged from r4, verified): each wave waits its own
// stage-t vmcnt before the barrier, so after the barrier buffer t is
// fully landed; buffer re-staged at iter t was last read at iter t-1,
// and every wave's ds_reads from it completed before its MFMAs (lgkmcnt
// inserted by compiler), hence before it reached barrier t.
#define GEMM_LOOP(KITERS)                                                    \
    GEMM_STAGE(0, 0)                                                         \
    GEMM_STAGE(1, 32)                                                        \
    {                                                                        \
        int ri = 0, ni = 1, si = 2;                                          \
        for (int t = 0; t < (KITERS); ++t) {                                 \
            if (t < (KITERS) - 1)                                            \
                asm volatile("s_waitcnt vmcnt(3)" ::: "memory");             \
            else                                                             \
                asm volatile("s_waitcnt vmcnt(0)" ::: "memory");             \
            __builtin_amdgcn_s_barrier();                                    \
            asm volatile("" ::: "memory");                                   \
            if (t + 2 < (KITERS)) { GEMM_STAGE(si, (t + 2) * 32) }           \
            GEMM_MFMA(ri)                                                    \
            int tmp = ri; ri = ni; ni = si; si = tmp;                        \
        }                                                                    \
    }

// shared GEMM1: H1 = silu(Xh @ Ws1), fp16. M=2048 N=4096 K=1024.
__global__ __launch_bounds__(256) void g_shared1(const f16* __restrict__ Xh,
                                                 const f16* __restrict__ Bt,  // [FF][HD]
                                                 f16* __restrict__ H1)
{
    GEMM_LDS
    GEMM_PREAMBLE
    const int m0 = blockIdx.y * 64, n0 = blockIdx.x * 128;
    const f16* gA = Xh + (size_t)(m0 + wave * 16 + sr) * HD + sc;
    const f16* gB0 = Bt + (size_t)(n0 + wave * 32 + sr) * HD + sc;
    const f16* gB1 = gB0 + (size_t)16 * HD;

    f32x4 acc[2][4] = {};
    GEMM_LOOP(HD / 32)

    #pragma unroll
    for (int i = 0; i < 2; ++i)
        #pragma unroll
        for (int j = 0; j < 4; ++j)
            #pragma unroll
            for (int r = 0; r < 4; ++r) {
                int m = m0 + wm + i * 16 + q * 4 + r;
                int n = n0 + wn + j * 16 + fr;
                float v = acc[i][j][r];
                H1[(size_t)m * FF + n] = (f16)(v / (1.f + expf(-v)));
            }
}

// shared GEMM2: Out += H1 @ Ws2, split-K=4 atomics. M=2048 N=1024 K=4096.
__global__ __launch_bounds__(256) void g_shared2(const f16* __restrict__ H1,
                                                 const f16* __restrict__ Bt,  // [HD][FF]
                                                 float* __restrict__ Out)
{
    GEMM_LDS
    GEMM_PREAMBLE
    const int m0 = blockIdx.y * 64, n0 = blockIdx.x * 128;
    const int kbase = blockIdx.z * (FF / 4);
    const f16* gA = H1 + (size_t)(m0 + wave * 16 + sr) * FF + kbase + sc;
    const f16* gB0 = Bt + (size_t)(n0 + wave * 32 + sr) * FF + kbase + sc;
    const f16* gB1 = gB0 + (size_t)16 * FF;

    f32x4 acc[2][4] = {};
    GEMM_LOOP((FF / 4) / 32)

    #pragma unroll
    for (int i = 0; i < 2; ++i)
        #pragma unroll
        for (int j = 0; j < 4; ++j)
            #pragma unroll
            for (int r = 0; r < 4; ++r) {
                int m = m0 + wm + i * 16 + q * 4 + r;
                int n = n0 + wn + j * 16 + fr;
                atomicAdd(&Out[(size_t)m * HD + n], acc[i][j][r]);
            }
}

// expert GEMM1: Hx[slot] = silu(Xh[rtok[slot]] @ W1[e]) fp16. K=1024 N=512.
__global__ __launch_bounds__(256) void g_exp1(const f16* __restrict__ Xh,
                                              const f16* __restrict__ W1t, // [E][M][H]
                                              const int* __restrict__ counts,
                                              const int* __restrict__ offsets,
                                              const int* __restrict__ rtok,
                                              f16* __restrict__ Hx)
{
    const int e = blockIdx.z;
    const int cnt = counts[e];
    const int mt = blockIdx.y * 64;
    if (mt >= cnt) return;
    const int off = offsets[e];
    const int n0 = blockIdx.x * 128;
    const f16* W = W1t + (size_t)e * MD * HD;

    GEMM_LDS
    GEMM_PREAMBLE

    int rm = mt + wave * 16 + sr;
    int s0 = off + (rm < cnt ? rm : cnt - 1);
    const f16* gA = Xh + (size_t)rtok[s0] * HD + sc;
    const f16* gB0 = W + (size_t)(n0 + wave * 32 + sr) * HD + sc;
    const f16* gB1 = gB0 + (size_t)16 * HD;

    f32x4 acc[2][4] = {};
    GEMM_LOOP(HD / 32)

    #pragma unroll
    for (int i = 0; i < 2; ++i)
        #pragma unroll
        for (int j = 0; j < 4; ++j)
            #pragma unroll
            for (int r = 0; r < 4; ++r) {
                int m_in = mt + wm + i * 16 + q * 4 + r;
                if (m_in < cnt) {
                    int n = n0 + wn + j * 16 + fr;
                    float v = acc[i][j][r];
                    Hx[(size_t)(off + m_in) * MD + n] = (f16)(v / (1.f + expf(-v)));
                }
            }
}

// expert GEMM2: Out[t] += w * (Hx @ W2[e]). K=512 N=1024, atomic scatter.
__global__ __launch_bounds__(256) void g_exp2(const f16* __restrict__ Hx,
                                              const f16* __restrict__ W2t, // [E][H][M]
                                              const int* __restrict__ counts,
                                              const int* __restrict__ offsets,
                                              const int* __restrict__ rtok,
                                              const float* __restrict__ rw,
                                              float* __restrict__ Out)
{
    const int e = blockIdx.z;
    const int cnt = counts[e];
    const int mt = blockIdx.y * 64;
    if (mt >= cnt) return;
    const int off = offsets[e];
    const int n0 = blockIdx.x * 128;
    const f16* W = W2t + (size_t)e * HD * MD;

    GEMM_LDS
    GEMM_PREAMBLE

    // A rows are packed slots; Hx pad rows (128) make OOB reads safe
    // (masked at C).
    const f16* gA = Hx + (size_t)(off + mt + wave * 16 + sr) * MD + sc;
    const f16* gB0 = W + (size_t)(n0 + wave * 32 + sr) * MD + sc;
    const f16* gB1 = gB0 + (size_t)16 * MD;

    f32x4 acc[2][4] = {};
    GEMM_LOOP(MD / 32)

    #pragma unroll
    for (int i = 0; i < 2; ++i)
        #pragma unroll
        for (int r = 0; r < 4; ++r) {
            int m_in = mt + wm + i * 16 + q * 4 + r;
            if (m_in < cnt) {
                int slot = off + m_in;
                int t = rtok[slot];
                float w = rw[slot];
                float* orow = Out + (size_t)t * HD + n0 + wn + fr;
                #pragma unroll
                for (int j = 0; j < 4; ++j)
                    atomicAdd(&orow[j * 16], w * acc[i][j][r]);
            }
        }
}

// ------------------------------------------------------------------
extern "C" void kernel_launch(void* const* d_in, const int* in_sizes, int n_in,
                              void* d_out, int out_size, void* d_ws, size_t ws_size,
                              hipStream_t stream)
{
    (void)in_sizes; (void)n_in; (void)out_size; (void)ws_size;
    const float* X   = (const float*)d_in[0];
    const float* Ws1 = (const float*)d_in[1];
    const float* Ws2 = (const float*)d_in[2];
    const float* Wg  = (const float*)d_in[3];
    const float* W1  = (const float*)d_in[4];
    const float* W2  = (const float*)d_in[5];
    float* out = (float*)d_out;
    float* logits = out + (size_t)NT * HD;

    char* ws = (char*)d_ws;
    f16*   h1       = (f16*)(ws + O_H1);
    f16*   hx       = (f16*)(ws + O_HX);
    int*   topk_idx = (int*)(ws + O_TOPKI);
    float* topk_w   = (float*)(ws + O_TOPKW);
    int*   counts   = (int*)(ws + O_COUNTS);
    int*   cursors  = (int*)(ws + O_CURSORS);
    int*   offsets  = (int*)(ws + O_OFFSETS);
    int*   rtok     = (int*)(ws + O_RTOK);
    float* rwt      = (float*)(ws + O_RW);
    f16*   xh       = (f16*)(ws + O_XH);
    f16*   w1t      = (f16*)(ws + O_W1T);
    f16*   w2t      = (f16*)(ws + O_W2T);
    f16*   ws1t     = (f16*)(ws + O_WS1T);
    f16*   ws2t     = (f16*)(ws + O_WS2T);

    hipMemsetAsync(counts, 0, 512, stream);   // counts + cursors

    k_router<<<NT / 4, 256, 0, stream>>>(X, Wg, logits);
    k_topk<<<NT, 64, 0, stream>>>(logits, topk_idx, topk_w, counts);
    k_scan<<<1, 64, 0, stream>>>(counts, offsets);
    k_route<<<NT * TOPK / 256, 256, 0, stream>>>(topk_idx, topk_w, offsets, cursors, rtok, rwt);

    // conversion pre-pass
    k_cvt_x<<<NT * HD / 1024, 256, 0, stream>>>(X, xh);
    k_cvt_t<<<dim3(FF / 64, HD / 64, 1), 256, 0, stream>>>(Ws1, ws1t, HD, FF);
    k_cvt_t<<<dim3(HD / 64, FF / 64, 1), 256, 0, stream>>>(Ws2, ws2t, FF, HD);
    k_cvt_t<<<dim3(MD / 64, HD / 64, NE), 256, 0, stream>>>(W1, w1t, HD, MD);
    k_cvt_t<<<dim3(HD / 64, MD / 64, NE), 256, 0, stream>>>(W2, w2t, MD, HD);
    hipMemsetAsync(out, 0, (size_t)NT * HD * 4, stream);

    g_shared1<<<dim3(FF / 128, NT / 64), 256, 0, stream>>>(xh, ws1t, h1);
    g_shared2<<<dim3(HD / 128, NT / 64, 4), 256, 0, stream>>>(h1, ws2t, out);
    g_exp1<<<dim3(MD / 128, NT / 64, NE), 256, 0, stream>>>(xh, w1t, counts, offsets, rtok, hx);
    g_exp2<<<dim3(HD / 128, NT / 64, NE), 256, 0, stream>>>(hx, w2t, counts, offsets, rtok, rwt, out);
}